// Round 3
// baseline (285.330 us; speedup 1.0000x reference)
//
#include <hip/hip_runtime.h>
#include <hip/hip_bf16.h>

#define M_ROWS 512
#define N_COLS 15080
#define K_DIM  2048
#define BM 128
#define BN 128
#define BKF 64                 // K elements per k-step
#define NT 118                 // ceil(15080/128)
#define KSTEPS (K_DIM / BKF)   // 32
#define SCALE 20.0f            // 1/TEMP

typedef _Float16 f16x8 __attribute__((ext_vector_type(8)));
typedef float    f32x4 __attribute__((ext_vector_type(4)));

// ---------------------------------------------------------------------------
// Kernel 1: tiled MFMA GEMM (fp32 -> fp16 on the fly) + fused per-tile
// logsumexp partials.  grid = 4 * 118 blocks, 256 threads (4 waves, 2x2).
// Each block computes a 128x128 tile of s = 20 * F @ Bank^T, then writes
// per-(row, ntile) partial max / partial sum(exp) and the target logit t_b.
//
// blockIdx -> (mi, nt) mapping co-locates the 4 M-tile blocks sharing one
// 1 MB B panel on the SAME XCD (indices congruent mod 8) so the panel is
// HBM-fetched once and L2-served 3x (T1: consecutive blockIdx round-robins
// over the 8 XCDs; stride-8 -> same XCD).
// ---------------------------------------------------------------------------
extern "C" __global__ __launch_bounds__(256, 2)
void k_gemm_lse(const float* __restrict__ A,   // features  [512][2048]
                const float* __restrict__ Bk,  // bank      [15080][2048]
                const int*   __restrict__ gt,  // gt_labels [512][5]
                float* __restrict__ pm,        // [NT][512] partial max
                float* __restrict__ ps,        // [NT][512] partial sumexp
                float* __restrict__ tv)        // [512] target logits
{
    __shared__ __align__(16) ushort lds[16384];  // 32 KB: A plane 16K, B plane 16K

    const int t  = threadIdx.x;
    const int bx = blockIdx.x;

    // ---- XCD co-location swizzle: same-nt blocks get indices == (mod 8) ----
    int mi, nt;
    if (bx < 448) {                 // 14 full chunks of 8 nt-groups
        const int slot = bx & 7;    // XCD slot
        const int rest = bx >> 3;   // 0..55
        mi = rest & 3;
        nt = (rest >> 2) * 8 + slot;   // 0..111
    } else {                        // tail: nt 112..117
        const int r2 = bx - 448;    // 0..23
        mi = r2 & 3;
        nt = 112 + (r2 >> 2);
    }
    const int rowA0 = mi * BM;
    const int rowB0 = nt * BN;

    // staging geometry: 1024 16B-granules per plane / 256 threads = 4 each
    int arow[4], ag[4];
#pragma unroll
    for (int i = 0; i < 4; i++) { int G = t + i * 256; arow[i] = G >> 3; ag[i] = G & 7; }

    float4 ra[8], rb[8];
    auto LOAD = [&](int kt) {
#pragma unroll
        for (int i = 0; i < 4; i++) {
            const float* pa = A + (size_t)(rowA0 + arow[i]) * K_DIM + kt * BKF + ag[i] * 8;
            ra[2 * i]     = *(const float4*)(pa);
            ra[2 * i + 1] = *(const float4*)(pa + 4);
            const int br = rowB0 + arow[i];
            if (br < N_COLS) {
                const float* pb = Bk + (size_t)br * K_DIM + kt * BKF + ag[i] * 8;
                rb[2 * i]     = *(const float4*)(pb);
                rb[2 * i + 1] = *(const float4*)(pb + 4);
            } else {
                rb[2 * i]     = make_float4(0.f, 0.f, 0.f, 0.f);
                rb[2 * i + 1] = make_float4(0.f, 0.f, 0.f, 0.f);
            }
        }
    };
    auto STORE = [&]() {
#pragma unroll
        for (int i = 0; i < 4; i++) {
            const int ba = (arow[i] * 128 + ag[i] * 16) ^ ((arow[i] & 7) << 4);
            f16x8 ha, hb;
            float4 x = ra[2 * i], y = ra[2 * i + 1];
            ha[0] = (_Float16)x.x; ha[1] = (_Float16)x.y; ha[2] = (_Float16)x.z; ha[3] = (_Float16)x.w;
            ha[4] = (_Float16)y.x; ha[5] = (_Float16)y.y; ha[6] = (_Float16)y.z; ha[7] = (_Float16)y.w;
            x = rb[2 * i]; y = rb[2 * i + 1];
            hb[0] = (_Float16)x.x; hb[1] = (_Float16)x.y; hb[2] = (_Float16)x.z; hb[3] = (_Float16)x.w;
            hb[4] = (_Float16)y.x; hb[5] = (_Float16)y.y; hb[6] = (_Float16)y.z; hb[7] = (_Float16)y.w;
            *(f16x8*)((char*)lds + ba)         = ha;
            *(f16x8*)((char*)lds + 16384 + ba) = hb;
        }
    };

    // fragment read addresses (constant over kt; swizzle XOR only touches bits 4-6)
    const int lane = t & 63;
    const int wid  = t >> 6;
    const int wm = wid >> 1, wn = wid & 1;
    const int q = lane >> 4, r = lane & 15;
    int aaddr[4][2], baddr[4][2];
#pragma unroll
    for (int m = 0; m < 4; m++) {
        const int rowa = wm * 64 + m * 16 + r;
        const int rowb = wn * 64 + m * 16 + r;
#pragma unroll
        for (int ks = 0; ks < 2; ks++) {
            aaddr[m][ks] = (rowa * 128 + ks * 64 + q * 16) ^ ((rowa & 7) << 4);
            baddr[m][ks] = 16384 + ((rowb * 128 + ks * 64 + q * 16) ^ ((rowb & 7) << 4));
        }
    }

    f32x4 acc[4][4];
    const f32x4 zero = {0.f, 0.f, 0.f, 0.f};
#pragma unroll
    for (int m = 0; m < 4; m++)
#pragma unroll
        for (int n = 0; n < 4; n++) acc[m][n] = zero;

    LOAD(0);
    for (int kt = 0; kt < KSTEPS; kt++) {
        __syncthreads();          // previous iter's LDS reads complete
        STORE();
        __syncthreads();
        if (kt + 1 < KSTEPS) LOAD(kt + 1);   // prefetch hides under MFMA

        // Read all B fragments once (32 VGPRs), stream A fragments per-m
        // (8 VGPRs live) -> peak pressure ~200 regs, no spill at the
        // __launch_bounds__(256,2) 256-VGPR cap.
        f16x8 bf[4][2];
#pragma unroll
        for (int n = 0; n < 4; n++)
#pragma unroll
            for (int ks = 0; ks < 2; ks++)
                bf[n][ks] = *(const f16x8*)((const char*)lds + baddr[n][ks]);
#pragma unroll
        for (int m = 0; m < 4; m++) {
            const f16x8 af0 = *(const f16x8*)((const char*)lds + aaddr[m][0]);
            const f16x8 af1 = *(const f16x8*)((const char*)lds + aaddr[m][1]);
#pragma unroll
            for (int n = 0; n < 4; n++) {
                acc[m][n] = __builtin_amdgcn_mfma_f32_16x16x32_f16(af0, bf[n][0], acc[m][n], 0, 0, 0);
                acc[m][n] = __builtin_amdgcn_mfma_f32_16x16x32_f16(af1, bf[n][1], acc[m][n], 0, 0, 0);
            }
        }
    }

    // ---------------- epilogue: fused per-tile logsumexp partials ----------
    __syncthreads();                       // done with tile LDS; reuse it
    float* redm = (float*)lds;             // [2][128]
    float* reds = ((float*)lds) + 256;     // [2][128]

#pragma unroll
    for (int m = 0; m < 4; m++) {
#pragma unroll
        for (int j = 0; j < 4; j++) {
            const int lrow = wm * 64 + m * 16 + q * 4 + j;
            const int grow = rowA0 + lrow;
            const int pid  = gt[grow * 5 + 4];
            float sv[4];
            float mx = -INFINITY;
#pragma unroll
            for (int n = 0; n < 4; n++) {
                const int gc = rowB0 + wn * 64 + n * 16 + r;
                float s = SCALE * acc[m][n][j];
                s = (gc < N_COLS) ? s : -INFINITY;
                sv[n] = s;
                mx = fmaxf(mx, s);
                if (gc == pid) tv[grow] = s;   // unique writer across grid
            }
            // reduce over the 16 lanes sharing this output row (cols)
#pragma unroll
            for (int d = 1; d < 16; d <<= 1) mx = fmaxf(mx, __shfl_xor(mx, d, 16));
            float se = 0.f;
#pragma unroll
            for (int n = 0; n < 4; n++) se += __expf(sv[n] - mx);
#pragma unroll
            for (int d = 1; d < 16; d <<= 1) se += __shfl_xor(se, d, 16);
            if (r == 0) { redm[wn * 128 + lrow] = mx; reds[wn * 128 + lrow] = se; }
        }
    }
    __syncthreads();
    if (t < 128) {
        const float m0 = redm[t], m1 = redm[128 + t];
        const float s0 = reds[t], s1 = reds[128 + t];
        const float Mv = fmaxf(m0, m1);
        const float Sv = s0 * __expf(m0 - Mv) + s1 * __expf(m1 - Mv);
        pm[nt * 512 + rowA0 + t] = Mv;
        ps[nt * 512 + rowA0 + t] = Sv;
    }
}

// ---------------------------------------------------------------------------
// Kernel 2: merge NT partials per row -> logsumexp, subtract target, mean.
// ---------------------------------------------------------------------------
extern "C" __global__ void k_reduce(const float* __restrict__ pm,
                                    const float* __restrict__ ps,
                                    const float* __restrict__ tv,
                                    float* __restrict__ out)
{
    __shared__ float red[512];
    const int b = threadIdx.x;
    float M = -INFINITY;
    for (int i = 0; i < NT; i++) M = fmaxf(M, pm[i * 512 + b]);
    float S = 0.f;
    for (int i = 0; i < NT; i++) S += ps[i * 512 + b] * __expf(pm[i * 512 + b] - M);
    const float lb = M + logf(S) - tv[b];   // -logp of target
    red[b] = lb;
    __syncthreads();
    for (int s = 256; s > 0; s >>= 1) {
        if (b < s) red[b] += red[b + s];
        __syncthreads();
    }
    if (b == 0) out[0] = red[0] / 512.0f;
}

extern "C" void kernel_launch(void* const* d_in, const int* in_sizes, int n_in,
                              void* d_out, int out_size, void* d_ws, size_t ws_size,
                              hipStream_t stream)
{
    const float* feat = (const float*)d_in[0];   // features (512,2048)
    const int*   gt   = (const int*)d_in[2];     // gt_labels (512,5)
    const float* bank = (const float*)d_in[4];   // bank_features (15080,2048)

    float* pm = (float*)d_ws;            // [NT][512]
    float* ps = pm + NT * 512;           // [NT][512]
    float* tv = ps + NT * 512;           // [512]

    k_gemm_lse<<<dim3(4 * NT), 256, 0, stream>>>(feat, bank, gt, pm, ps, tv);
    k_reduce<<<1, 512, 0, stream>>>(pm, ps, tv, (float*)d_out);
}

// Round 4
// 250.129 us; speedup vs baseline: 1.1407x; 1.1407x over previous
//
#include <hip/hip_runtime.h>
#include <hip/hip_bf16.h>

#define M_ROWS 512
#define N_COLS 15080
#define K_DIM  2048
#define BM 128
#define BN 128
#define BKF 64                 // K elements per k-step
#define NT 118                 // ceil(15080/128)
#define KSTEPS (K_DIM / BKF)   // 32
#define SCALE 20.0f            // 1/TEMP

typedef _Float16 f16x8 __attribute__((ext_vector_type(8)));
typedef float    f32x4 __attribute__((ext_vector_type(4)));

// ---------------------------------------------------------------------------
// Kernel 1: tiled MFMA GEMM (fp32 -> fp16 on the fly) + fused per-tile
// logsumexp partials.  grid = 4*118 = 472 blocks, 512 threads (8 waves, 2x4).
// 472 blocks / 256 CUs ~ 1.84 blocks/CU -> 8-wave blocks give ~15 waves/CU
// (~46% occupancy) vs 7 waves/CU with 4-wave blocks (the round-3 limiter).
//
// blockIdx -> (mi, nt) co-locates the 4 M-tile blocks sharing one 1 MB
// B panel on the SAME XCD (indices congruent mod 8): panel HBM-fetched once,
// L2-served 3x (T1: consecutive blockIdx round-robin over 8 XCDs).
// ---------------------------------------------------------------------------
extern "C" __global__ __launch_bounds__(512, 4)
void k_gemm_lse(const float* __restrict__ A,   // features  [512][2048]
                const float* __restrict__ Bk,  // bank      [15080][2048]
                const int*   __restrict__ gt,  // gt_labels [512][5]
                float* __restrict__ pm,        // [512][NT] partial max
                float* __restrict__ ps,        // [512][NT] partial sumexp
                float* __restrict__ tv)        // [512] target logits
{
    __shared__ __align__(16) ushort lds[16384];  // 32 KB: A plane 16K, B plane 16K

    const int t  = threadIdx.x;
    const int bx = blockIdx.x;

    // ---- XCD co-location swizzle: same-nt blocks get indices == (mod 8) ----
    int mi, nt;
    if (bx < 448) {                 // 14 full chunks of 8 nt-groups
        const int slot = bx & 7;    // XCD slot
        const int rest = bx >> 3;   // 0..55
        mi = rest & 3;
        nt = (rest >> 2) * 8 + slot;   // 0..111
    } else {                        // tail: nt 112..117
        const int r2 = bx - 448;    // 0..23
        mi = r2 & 3;
        nt = 112 + (r2 >> 2);
    }
    const int rowA0 = mi * BM;
    const int rowB0 = nt * BN;

    // staging: 1024 16B-granules per plane / 512 threads = 2 each
    int arow[2], ag[2];
#pragma unroll
    for (int i = 0; i < 2; i++) { int G = t + i * 512; arow[i] = G >> 3; ag[i] = G & 7; }

    float4 ra[4], rb[4];
    auto LOAD = [&](int kt) {
#pragma unroll
        for (int i = 0; i < 2; i++) {
            const float* pa = A + (size_t)(rowA0 + arow[i]) * K_DIM + kt * BKF + ag[i] * 8;
            ra[2 * i]     = *(const float4*)(pa);
            ra[2 * i + 1] = *(const float4*)(pa + 4);
            const int br = rowB0 + arow[i];
            if (br < N_COLS) {
                const float* pb = Bk + (size_t)br * K_DIM + kt * BKF + ag[i] * 8;
                rb[2 * i]     = *(const float4*)(pb);
                rb[2 * i + 1] = *(const float4*)(pb + 4);
            } else {
                rb[2 * i]     = make_float4(0.f, 0.f, 0.f, 0.f);
                rb[2 * i + 1] = make_float4(0.f, 0.f, 0.f, 0.f);
            }
        }
    };
    auto STORE = [&]() {
#pragma unroll
        for (int i = 0; i < 2; i++) {
            const int ba = (arow[i] * 128 + ag[i] * 16) ^ ((arow[i] & 7) << 4);
            f16x8 ha, hb;
            float4 x = ra[2 * i], y = ra[2 * i + 1];
            ha[0] = (_Float16)x.x; ha[1] = (_Float16)x.y; ha[2] = (_Float16)x.z; ha[3] = (_Float16)x.w;
            ha[4] = (_Float16)y.x; ha[5] = (_Float16)y.y; ha[6] = (_Float16)y.z; ha[7] = (_Float16)y.w;
            x = rb[2 * i]; y = rb[2 * i + 1];
            hb[0] = (_Float16)x.x; hb[1] = (_Float16)x.y; hb[2] = (_Float16)x.z; hb[3] = (_Float16)x.w;
            hb[4] = (_Float16)y.x; hb[5] = (_Float16)y.y; hb[6] = (_Float16)y.z; hb[7] = (_Float16)y.w;
            *(f16x8*)((char*)lds + ba)         = ha;
            *(f16x8*)((char*)lds + 16384 + ba) = hb;
        }
    };

    // wave grid: 2 (M) x 4 (N).  Wave tile 64x32 -> acc[4][2] (32 VGPRs).
    const int lane = t & 63;
    const int wid  = t >> 6;
    const int wm = wid >> 2, wn = wid & 3;
    const int q = lane >> 4, r = lane & 15;
    int aaddr[4][2], baddr[2][2];
#pragma unroll
    for (int m = 0; m < 4; m++) {
        const int rowa = wm * 64 + m * 16 + r;
#pragma unroll
        for (int ks = 0; ks < 2; ks++)
            aaddr[m][ks] = (rowa * 128 + ks * 64 + q * 16) ^ ((rowa & 7) << 4);
    }
#pragma unroll
    for (int n = 0; n < 2; n++) {
        const int rowb = wn * 32 + n * 16 + r;
#pragma unroll
        for (int ks = 0; ks < 2; ks++)
            baddr[n][ks] = 16384 + ((rowb * 128 + ks * 64 + q * 16) ^ ((rowb & 7) << 4));
    }

    f32x4 acc[4][2];
    const f32x4 zero = {0.f, 0.f, 0.f, 0.f};
#pragma unroll
    for (int m = 0; m < 4; m++)
#pragma unroll
        for (int n = 0; n < 2; n++) acc[m][n] = zero;

    LOAD(0);
    for (int kt = 0; kt < KSTEPS; kt++) {
        __syncthreads();          // previous iter's LDS reads complete
        STORE();
        __syncthreads();
        if (kt + 1 < KSTEPS) LOAD(kt + 1);   // prefetch hides under MFMA

        f16x8 bf[2][2];
#pragma unroll
        for (int n = 0; n < 2; n++)
#pragma unroll
            for (int ks = 0; ks < 2; ks++)
                bf[n][ks] = *(const f16x8*)((const char*)lds + baddr[n][ks]);
#pragma unroll
        for (int m = 0; m < 4; m++) {
            const f16x8 af0 = *(const f16x8*)((const char*)lds + aaddr[m][0]);
            const f16x8 af1 = *(const f16x8*)((const char*)lds + aaddr[m][1]);
#pragma unroll
            for (int n = 0; n < 2; n++) {
                acc[m][n] = __builtin_amdgcn_mfma_f32_16x16x32_f16(af0, bf[n][0], acc[m][n], 0, 0, 0);
                acc[m][n] = __builtin_amdgcn_mfma_f32_16x16x32_f16(af1, bf[n][1], acc[m][n], 0, 0, 0);
            }
        }
    }

    // ---------------- epilogue: fused per-tile logsumexp partials ----------
    __syncthreads();                       // done with tile LDS; reuse it
    float* redm = (float*)lds;             // [4][128]  per-wn-column partial max
    float* reds = ((float*)lds) + 512;     // [4][128]  per-wn-column partial sum

#pragma unroll
    for (int m = 0; m < 4; m++) {
#pragma unroll
        for (int j = 0; j < 4; j++) {
            const int lrow = wm * 64 + m * 16 + q * 4 + j;
            const int grow = rowA0 + lrow;
            const int pid  = gt[grow * 5 + 4];
            float sv[2];
            float mx = -INFINITY;
#pragma unroll
            for (int n = 0; n < 2; n++) {
                const int gc = rowB0 + wn * 32 + n * 16 + r;
                float s = SCALE * acc[m][n][j];
                s = (gc < N_COLS) ? s : -INFINITY;
                sv[n] = s;
                mx = fmaxf(mx, s);
                if (gc == pid) tv[grow] = s;   // unique writer across grid
            }
            // reduce over the 16 lanes sharing this output row (cols)
#pragma unroll
            for (int d = 1; d < 16; d <<= 1) mx = fmaxf(mx, __shfl_xor(mx, d, 16));
            float se = 0.f;
#pragma unroll
            for (int n = 0; n < 2; n++) se += __expf(sv[n] - mx);
#pragma unroll
            for (int d = 1; d < 16; d <<= 1) se += __shfl_xor(se, d, 16);
            if (r == 0) { redm[wn * 128 + lrow] = mx; reds[wn * 128 + lrow] = se; }
        }
    }
    __syncthreads();
    if (t < 128) {
        float Mv = -INFINITY;
#pragma unroll
        for (int c = 0; c < 4; c++) Mv = fmaxf(Mv, redm[c * 128 + t]);
        float Sv = 0.f;
#pragma unroll
        for (int c = 0; c < 4; c++) Sv += reds[c * 128 + t] * __expf(redm[c * 128 + t] - Mv);
        pm[(rowA0 + t) * NT + nt] = Mv;    // [row][NT] layout -> coalesced tail reads
        ps[(rowA0 + t) * NT + nt] = Sv;
    }
}

// ---------------------------------------------------------------------------
// Kernel 2: row-parallel LSE combine. 512 blocks x 128 threads; block b
// merges its row's NT partials -> rowloss[b] = LSE(row b) - tv[b].
// ---------------------------------------------------------------------------
extern "C" __global__ __launch_bounds__(128)
void k_rowlse(const float* __restrict__ pm,
              const float* __restrict__ ps,
              const float* __restrict__ tv,
              float* __restrict__ rowloss)
{
    const int b = blockIdx.x;
    const int i = threadIdx.x;
    __shared__ float wred[4];

    const float m = (i < NT) ? pm[b * NT + i] : -INFINITY;
    const float s = (i < NT) ? ps[b * NT + i] : 0.f;

    float M = m;
#pragma unroll
    for (int d = 1; d < 64; d <<= 1) M = fmaxf(M, __shfl_xor(M, d, 64));
    if ((i & 63) == 0) wred[i >> 6] = M;
    __syncthreads();
    M = fmaxf(wred[0], wred[1]);
    __syncthreads();

    float e = (i < NT) ? s * __expf(m - M) : 0.f;
#pragma unroll
    for (int d = 1; d < 64; d <<= 1) e += __shfl_xor(e, d, 64);
    if ((i & 63) == 0) wred[i >> 6] = e;
    __syncthreads();
    if (i == 0) {
        const float S = wred[0] + wred[1];
        rowloss[b] = M + logf(S) - tv[b];
    }
}

// ---------------------------------------------------------------------------
// Kernel 3: mean over 512 rows.
// ---------------------------------------------------------------------------
extern "C" __global__ __launch_bounds__(512)
void k_final(const float* __restrict__ rowloss, float* __restrict__ out)
{
    __shared__ float red[512];
    const int b = threadIdx.x;
    red[b] = rowloss[b];
    __syncthreads();
    for (int s = 256; s > 0; s >>= 1) {
        if (b < s) red[b] += red[b + s];
        __syncthreads();
    }
    if (b == 0) out[0] = red[0] / 512.0f;
}

extern "C" void kernel_launch(void* const* d_in, const int* in_sizes, int n_in,
                              void* d_out, int out_size, void* d_ws, size_t ws_size,
                              hipStream_t stream)
{
    const float* feat = (const float*)d_in[0];   // features (512,2048)
    const int*   gt   = (const int*)d_in[2];     // gt_labels (512,5)
    const float* bank = (const float*)d_in[4];   // bank_features (15080,2048)

    float* pm = (float*)d_ws;            // [512][NT]
    float* ps = pm + 512 * NT;           // [512][NT]
    float* tv = ps + 512 * NT;           // [512]
    float* rl = tv + 512;                // [512]

    k_gemm_lse<<<dim3(4 * NT), 512, 0, stream>>>(feat, bank, gt, pm, ps, tv);
    k_rowlse<<<dim3(512), 128, 0, stream>>>(pm, ps, tv, rl);
    k_final<<<dim3(1), 512, 0, stream>>>(rl, (float*)d_out);
}